// Round 1
// baseline (178.538 us; speedup 1.0000x reference)
//
#include <hip/hip_runtime.h>

#define HH 512        // sinogram height (H_IN)
#define WW 360        // angles (W_IN)
#define NB 4          // batch
#define DD 512        // output D

// ws layout in floats
#define OFF_TAB  0                          // float2 tab[360] (A,B) -> 720 floats, padded to 1024
#define OFF_RT   1024                       // radonT [4][360][512]
#define OFF_FILT (1024 + NB*WW*HH)          // filt4 [360][512][4]
#define OFF_PART (OFF_FILT + WW*HH*NB)      // parts [4][4][512][512]
#define CHUNK_ELEMS (NB*DD*DD)

// ---------------- K0a: angle table ----------------
// py = A*(j-256) + B*(i-256) + 255.5 ; A = cos(th)*255.5/256, B = -sin(th)*255.5/256
__global__ void k_tab(float* __restrict__ ws) {
    int w = threadIdx.x;
    if (w < WW) {
        double th = (3.14159265358979323846 / 180.0) * (0.5 * (double)w);
        double c = cos(th), s = sin(th);
        float2 ab;
        ab.x = (float)(c * (255.5 / 256.0));
        ab.y = (float)(-s * (255.5 / 256.0));
        ((float2*)(ws + OFF_TAB))[w] = ab;
    }
}

// ---------------- K0b: transpose radon[n][h][w] -> radonT[n][w][h] ----------------
__global__ __launch_bounds__(256) void k_transpose(const float* __restrict__ radon,
                                                   float* __restrict__ ws) {
    __shared__ float tile[32][33];
    int n  = blockIdx.z;
    int w0 = blockIdx.x * 32, h0 = blockIdx.y * 32;
    int x = threadIdx.x, y = threadIdx.y;  // 32 x 8
    const float* rn = radon + n * (HH * WW);
#pragma unroll
    for (int r = 0; r < 32; r += 8) {
        int h = h0 + y + r, w = w0 + x;
        tile[y + r][x] = (w < WW) ? rn[h * WW + w] : 0.f;
    }
    __syncthreads();
    float* rt = ws + OFF_RT + n * (WW * HH);
#pragma unroll
    for (int r = 0; r < 32; r += 8) {
        int w = w0 + y + r, h = h0 + x;
        if (w < WW) rt[w * HH + h] = tile[x][y + r];
    }
}

// ---------------- K1: circular ramp filter ----------------
// filt4[w][y][n] = sum_d radonT[n][w][(257+y+d)&511] * hG[d]
__global__ __launch_bounds__(256) void k_filter(const float* __restrict__ hG,
                                                float* __restrict__ ws) {
    __shared__ float r2[NB][1024];          // r2[n][i] = col[(i+257)&511], duplicated span
    int wA  = blockIdx.x;
    int tid = threadIdx.x;
    const float* rt = ws + OFF_RT;
    for (int t = tid; t < NB * 1024; t += 256) {
        int n = t >> 10, i = t & 1023;
        r2[n][i] = rt[(n * WW + wA) * HH + ((i + 257) & 511)];
    }
    __syncthreads();

    int n = tid >> 6, lane = tid & 63, y0 = lane << 3;   // 8 consecutive y per thread
    float acc[8] = {0, 0, 0, 0, 0, 0, 0, 0};
    const float* rr = &r2[n][y0];
    float4 Wr0 = *(const float4*)(rr + 0);
    float4 Wr1 = *(const float4*)(rr + 4);
    float4 Wr2 = *(const float4*)(rr + 8);
    float4 Wr3 = *(const float4*)(rr + 12);

    for (int d = 0; d < 512; d += 8) {
        float hg[8];
#pragma unroll
        for (int q = 0; q < 8; ++q) hg[q] = hG[d + q];   // uniform index -> s_load
        float wf[16] = {Wr0.x, Wr0.y, Wr0.z, Wr0.w, Wr1.x, Wr1.y, Wr1.z, Wr1.w,
                        Wr2.x, Wr2.y, Wr2.z, Wr2.w, Wr3.x, Wr3.y, Wr3.z, Wr3.w};
#pragma unroll
        for (int du = 0; du < 8; ++du)
#pragma unroll
            for (int u = 0; u < 8; ++u)
                acc[u] = fmaf(wf[du + u], hg[du], acc[u]);
        if (d < 504) {                                    // slide window by 8
            Wr0 = Wr2; Wr1 = Wr3;
            Wr2 = *(const float4*)(rr + d + 16);
            Wr3 = *(const float4*)(rr + d + 20);
        }
    }
    float* filt = ws + OFF_FILT;
#pragma unroll
    for (int u = 0; u < 8; ++u)
        filt[(wA * HH + y0 + u) * NB + n] = acc[u];
}

// ---------------- K2: backprojection (4-angle-chunk split) ----------------
__global__ __launch_bounds__(256) void k_backproj(float* __restrict__ ws) {
    __shared__ float4 cols[HH + 1];                      // cols[y] = filt4[w][y][0..3]
    int lane  = threadIdx.x & 63;
    int ithr  = threadIdx.x >> 6;                        // 0..3
    int j     = blockIdx.x * 64 + lane;
    int i0    = blockIdx.y * 32 + ithr;                  // i = i0 + 4u
    int chunk = blockIdx.z;

    const float2* tab  = (const float2*)(ws + OFF_TAB);
    const float*  filt = ws + OFF_FILT;

    float acc[8][4];
#pragma unroll
    for (int u = 0; u < 8; ++u)
#pragma unroll
        for (int n = 0; n < 4; ++n) acc[u][n] = 0.f;

    float jf = (float)(j - 256);
    float ifl[8];
#pragma unroll
    for (int u = 0; u < 8; ++u) ifl[u] = (float)(i0 + 4 * u - 256);

    int wbeg = chunk * 90, wend = wbeg + 90;
    for (int w = wbeg; w < wend; ++w) {
        // stage this angle's 4 columns (512 float4 = 8KB), coalesced
        const float4* src = (const float4*)(filt + w * (HH * NB));
        for (int t = threadIdx.x; t < HH; t += 256) cols[t] = src[t];
        if (threadIdx.x == 0) cols[HH] = make_float4(0.f, 0.f, 0.f, 0.f);  // finite pad
        __syncthreads();

        float2 ab = tab[w];
        float A = ab.x, B = ab.y;
        float pybase = fmaf(A, jf, 255.5f);
#pragma unroll
        for (int u = 0; u < 8; ++u) {
            float py = fmaf(B, ifl[u], pybase);
            float fl = floorf(py);
            float fy = py - fl;
            int   y0 = (int)fl;
            int   c0 = min(max(y0, 0), 511);
            float w0 = (y0 >= 0 && y0 < 512)  ? 1.f - fy : 0.f;
            float w1 = (y0 >= -1 && y0 < 511) ? fy       : 0.f;
            float4 p0 = cols[c0];
            float4 p1 = cols[c0 + 1];
            bool neg = (y0 < 0);
            float v1x = neg ? p0.x : p1.x;
            float v1y = neg ? p0.y : p1.y;
            float v1z = neg ? p0.z : p1.z;
            float v1w = neg ? p0.w : p1.w;
            acc[u][0] = fmaf(p0.x, w0, fmaf(v1x, w1, acc[u][0]));
            acc[u][1] = fmaf(p0.y, w0, fmaf(v1y, w1, acc[u][1]));
            acc[u][2] = fmaf(p0.z, w0, fmaf(v1z, w1, acc[u][2]));
            acc[u][3] = fmaf(p0.w, w0, fmaf(v1w, w1, acc[u][3]));
        }
        __syncthreads();
    }

    float* part = ws + OFF_PART + chunk * CHUNK_ELEMS;
#pragma unroll
    for (int n = 0; n < 4; ++n)
#pragma unroll
        for (int u = 0; u < 8; ++u)
            part[(n * DD + (i0 + 4 * u)) * DD + j] = acc[u][n];
}

// ---------------- K3: reduce chunks + scale ----------------
__global__ __launch_bounds__(256) void k_reduce(float* __restrict__ out,
                                                const float* __restrict__ ws) {
    int t = blockIdx.x * 256 + threadIdx.x;
    const float* p = ws + OFF_PART;
    float v = ((p[t] + p[t + CHUNK_ELEMS]) + p[t + 2 * CHUNK_ELEMS]) + p[t + 3 * CHUNK_ELEMS];
    out[t] = v * (float)(3.14159265358979323846 / 720.0);
}

extern "C" void kernel_launch(void* const* d_in, const int* in_sizes, int n_in,
                              void* d_out, int out_size, void* d_ws, size_t ws_size,
                              hipStream_t stream) {
    const float* radon = (const float*)d_in[0];
    const float* hG    = (const float*)d_in[1];
    // d_in[2] (t_y, 377MB) intentionally unused: recomputed analytically.
    float* out = (float*)d_out;
    float* ws  = (float*)d_ws;

    k_tab<<<1, 384, 0, stream>>>(ws);
    k_transpose<<<dim3(12, 16, 4), dim3(32, 8), 0, stream>>>(radon, ws);
    k_filter<<<WW, 256, 0, stream>>>(hG, ws);
    k_backproj<<<dim3(8, 16, 4), 256, 0, stream>>>(ws);
    k_reduce<<<4096, 256, 0, stream>>>(out, ws);
}

// Round 2
// 135.811 us; speedup vs baseline: 1.3146x; 1.3146x over previous
//
#include <hip/hip_runtime.h>

#define HH 512        // sinogram height (H_IN)
#define WW 360        // angles (W_IN)
#define NB 4          // batch
#define DD 512        // output D

// ws layout in floats
#define OFF_TAB  0                          // float2 tab[360] (A,B) -> 720 floats, padded to 1024
#define OFF_RT   1024                       // radonT [4][360][512]
#define OFF_FILT (1024 + NB*WW*HH)          // filt4 [360][512][4]
#define OFF_PART (OFF_FILT + WW*HH*NB)      // parts [4][4][512][512]
#define CHUNK_ELEMS (NB*DD*DD)

#define PAD   128
#define COLS_N 768                          // 128 pad | 512 data | 128 pad

#define GLOAD_LDS16(gp, lp)                                                   \
    __builtin_amdgcn_global_load_lds(                                         \
        (const __attribute__((address_space(1))) void*)(gp),                  \
        (__attribute__((address_space(3))) void*)(lp), 16, 0, 0)

// ---------------- K0a: angle table ----------------
// py = A*(j-256) + B*(i-256) + 255.5 ; A = cos(th)*255.5/256, B = -sin(th)*255.5/256
__global__ void k_tab(float* __restrict__ ws) {
    int w = threadIdx.x;
    if (w < WW) {
        double th = (3.14159265358979323846 / 180.0) * (0.5 * (double)w);
        double c = cos(th), s = sin(th);
        float2 ab;
        ab.x = (float)(c * (255.5 / 256.0));
        ab.y = (float)(-s * (255.5 / 256.0));
        ((float2*)(ws + OFF_TAB))[w] = ab;
    }
}

// ---------------- K0b: transpose radon[n][h][w] -> radonT[n][w][h] ----------------
__global__ __launch_bounds__(256) void k_transpose(const float* __restrict__ radon,
                                                   float* __restrict__ ws) {
    __shared__ float tile[32][33];
    int n  = blockIdx.z;
    int w0 = blockIdx.x * 32, h0 = blockIdx.y * 32;
    int x = threadIdx.x, y = threadIdx.y;  // 32 x 8
    const float* rn = radon + n * (HH * WW);
#pragma unroll
    for (int r = 0; r < 32; r += 8) {
        int h = h0 + y + r, w = w0 + x;
        tile[y + r][x] = (w < WW) ? rn[h * WW + w] : 0.f;
    }
    __syncthreads();
    float* rt = ws + OFF_RT + n * (WW * HH);
#pragma unroll
    for (int r = 0; r < 32; r += 8) {
        int w = w0 + y + r, h = h0 + x;
        if (w < WW) rt[w * HH + h] = tile[x][y + r];
    }
}

// ---------------- K1: circular ramp filter ----------------
// filt4[w][y][n] = sum_d radonT[n][w][(257+y+d)&511] * hG[d]
__global__ __launch_bounds__(256) void k_filter(const float* __restrict__ hG,
                                                float* __restrict__ ws) {
    __shared__ float r2[NB][1024];          // r2[n][i] = col[(i+257)&511], duplicated span
    int wA  = blockIdx.x;
    int tid = threadIdx.x;
    const float* rt = ws + OFF_RT;
    for (int t = tid; t < NB * 1024; t += 256) {
        int n = t >> 10, i = t & 1023;
        r2[n][i] = rt[(n * WW + wA) * HH + ((i + 257) & 511)];
    }
    __syncthreads();

    int n = tid >> 6, lane = tid & 63, y0 = lane << 3;   // 8 consecutive y per thread
    float acc[8] = {0, 0, 0, 0, 0, 0, 0, 0};
    const float* rr = &r2[n][y0];
    float4 Wr0 = *(const float4*)(rr + 0);
    float4 Wr1 = *(const float4*)(rr + 4);
    float4 Wr2 = *(const float4*)(rr + 8);
    float4 Wr3 = *(const float4*)(rr + 12);

    for (int d = 0; d < 512; d += 8) {
        float hg[8];
#pragma unroll
        for (int q = 0; q < 8; ++q) hg[q] = hG[d + q];   // uniform index -> s_load
        float wf[16] = {Wr0.x, Wr0.y, Wr0.z, Wr0.w, Wr1.x, Wr1.y, Wr1.z, Wr1.w,
                        Wr2.x, Wr2.y, Wr2.z, Wr2.w, Wr3.x, Wr3.y, Wr3.z, Wr3.w};
#pragma unroll
        for (int du = 0; du < 8; ++du)
#pragma unroll
            for (int u = 0; u < 8; ++u)
                acc[u] = fmaf(wf[du + u], hg[du], acc[u]);
        if (d < 504) {                                    // slide window by 8
            Wr0 = Wr2; Wr1 = Wr3;
            Wr2 = *(const float4*)(rr + d + 16);
            Wr3 = *(const float4*)(rr + d + 20);
        }
    }
    float* filt = ws + OFF_FILT;
#pragma unroll
    for (int u = 0; u < 8; ++u)
        filt[(wA * HH + y0 + u) * NB + n] = acc[u];
}

// ---------------- K2: backprojection ----------------
// Zero-padded cols (data at [PAD, PAD+512)) kills all boundary clamps/selects:
// out-of-range taps read 0 == reference's w0/w1 masking. Double-buffered,
// next angle staged via global_load_lds (DMA) while computing current.
__global__ __launch_bounds__(256) void k_backproj(float* __restrict__ ws) {
    __shared__ float4 cols[2][COLS_N];
    const int tid   = threadIdx.x;
    const int lane  = tid & 63;
    const int ithr  = tid >> 6;                        // 0..3
    const int j     = blockIdx.x * 64 + lane;
    const int i0    = blockIdx.y * 32 + ithr;          // i = i0 + 4u
    const int chunk = blockIdx.z;

    // zero ONLY the pad regions (never overlaps DMA region -> no write race)
    {
        int b = tid >> 7, r = tid & 127;               // 256 thr: 2 bufs x 128 rows
        float4 z = make_float4(0.f, 0.f, 0.f, 0.f);
        cols[b][r] = z;                                // low pad  [0,128)
        cols[b][PAD + HH + r] = z;                     // high pad [640,768)
    }

    const float2* tab  = (const float2*)(ws + OFF_TAB);
    const float*  filt = ws + OFF_FILT;

    float acc[8][4];
#pragma unroll
    for (int u = 0; u < 8; ++u)
#pragma unroll
        for (int n = 0; n < 4; ++n) acc[u][n] = 0.f;

    float jf = (float)(j - 256);
    float ifl[8];
#pragma unroll
    for (int u = 0; u < 8; ++u) ifl[u] = (float)(i0 + 4 * u - 256);

    const int wbeg = chunk * 90;

    // prologue: stage angle wbeg into buffer 0
    {
        const float4* src = (const float4*)(filt + (size_t)wbeg * (HH * NB));
#pragma unroll
        for (int c = 0; c < 2; ++c) {
            int idx = tid + c * 256;
            GLOAD_LDS16(src + idx, &cols[0][PAD + idx]);
        }
    }
    __syncthreads();   // drains vmcnt(0): DMA done, pads visible

    int cur = 0;
    for (int k = 0; k < 90; ++k) {
        const int w = wbeg + k;
        if (k + 1 < 90) {                              // stage next angle into other buf
            const float4* src = (const float4*)(filt + (size_t)(w + 1) * (HH * NB));
#pragma unroll
            for (int c = 0; c < 2; ++c) {
                int idx = tid + c * 256;
                GLOAD_LDS16(src + idx, &cols[cur ^ 1][PAD + idx]);
            }
        }

        float2 ab = tab[w];
        float pybase = fmaf(ab.x, jf, 255.5f + (float)PAD);
#pragma unroll
        for (int u = 0; u < 8; ++u) {
            float pyp = fmaf(ab.y, ifl[u], pybase);    // in [22, 745] -> trunc == floor
            int   c   = (int)pyp;
            float fy  = pyp - (float)c;
            float w0  = 1.f - fy;
            float4 p0 = cols[cur][c];
            float4 p1 = cols[cur][c + 1];
            acc[u][0] = fmaf(p1.x, fy, fmaf(p0.x, w0, acc[u][0]));
            acc[u][1] = fmaf(p1.y, fy, fmaf(p0.y, w0, acc[u][1]));
            acc[u][2] = fmaf(p1.z, fy, fmaf(p0.z, w0, acc[u][2]));
            acc[u][3] = fmaf(p1.w, fy, fmaf(p0.w, w0, acc[u][3]));
        }
        __syncthreads();   // all reads of cur done; DMA for cur^1 drained
        cur ^= 1;
    }

    float* part = ws + OFF_PART + (size_t)chunk * CHUNK_ELEMS;
#pragma unroll
    for (int n = 0; n < 4; ++n)
#pragma unroll
        for (int u = 0; u < 8; ++u)
            part[(n * DD + (i0 + 4 * u)) * DD + j] = acc[u][n];
}

// ---------------- K3: reduce chunks + scale (float4) ----------------
__global__ __launch_bounds__(256) void k_reduce(float* __restrict__ out,
                                                const float* __restrict__ ws) {
    int t = blockIdx.x * 256 + threadIdx.x;            // 262144 float4
    const float4* p = (const float4*)(ws + OFF_PART);
    const int C4 = CHUNK_ELEMS / 4;
    float4 a = p[t], b = p[t + C4], c = p[t + 2 * C4], d = p[t + 3 * C4];
    const float s = (float)(3.14159265358979323846 / 720.0);
    float4 r;
    r.x = ((a.x + b.x) + (c.x + d.x)) * s;
    r.y = ((a.y + b.y) + (c.y + d.y)) * s;
    r.z = ((a.z + b.z) + (c.z + d.z)) * s;
    r.w = ((a.w + b.w) + (c.w + d.w)) * s;
    ((float4*)out)[t] = r;
}

extern "C" void kernel_launch(void* const* d_in, const int* in_sizes, int n_in,
                              void* d_out, int out_size, void* d_ws, size_t ws_size,
                              hipStream_t stream) {
    const float* radon = (const float*)d_in[0];
    const float* hG    = (const float*)d_in[1];
    // d_in[2] (t_y, 377MB) intentionally unused: recomputed analytically.
    float* out = (float*)d_out;
    float* ws  = (float*)d_ws;

    k_tab<<<1, 384, 0, stream>>>(ws);
    k_transpose<<<dim3(12, 16, 4), dim3(32, 8), 0, stream>>>(radon, ws);
    k_filter<<<WW, 256, 0, stream>>>(hG, ws);
    k_backproj<<<dim3(8, 16, 4), 256, 0, stream>>>(ws);
    k_reduce<<<1024, 256, 0, stream>>>(out, ws);
}